// Round 4
// baseline (609.560 us; speedup 1.0000x reference)
//
#include <hip/hip_runtime.h>
#include <hip/hip_bf16.h>
#include <hip/hip_fp16.h>

#define B_ 4
#define N_ 4096
#define F_ 128
#define NEG (-1e30f)

typedef _Float16 f16;
typedef _Float16 half8 __attribute__((ext_vector_type(8)));
typedef float f32x4 __attribute__((ext_vector_type(4)));

// ---------------- k_wa: Wa[0:128) = W@a_src, Wa[128:256) = W@a_dst ----------
__global__ void k_wa(const float* __restrict__ W, const float* __restrict__ a_src,
                     const float* __restrict__ a_dst, float* __restrict__ Wa) {
    int f = threadIdx.x;  // 0..127
    const float4* Wr = (const float4*)(W + f * F_);
    const float4* As = (const float4*)a_src;
    const float4* Ad = (const float4*)a_dst;
    float s0 = 0.f, s1 = 0.f;
    #pragma unroll
    for (int o = 0; o < 32; ++o) {
        float4 w = Wr[o], s = As[o], d = Ad[o];
        s0 += w.x * s.x + w.y * s.y + w.z * s.z + w.w * s.w;
        s1 += w.x * d.x + w.y * d.y + w.z * d.z + w.w * d.w;
    }
    Wa[f] = s0;
    Wa[F_ + f] = s1;
}

// ---------------- k_h: h = x@W (fp32), stored transposed as f16 ------------
// hT[b][c][i] = h[b][i][c], per-batch layout (128, 4096)
__global__ __launch_bounds__(256) void k_h(const float* __restrict__ x,
                                           const float* __restrict__ W,
                                           f16* __restrict__ hT) {
    __shared__ float xs[16][128];
    int t = threadIdx.x;
    long R0 = (long)blockIdx.x * 16;  // global row base over B*N
    const float4* xg = (const float4*)(x + R0 * 128);
    float4* xsv = (float4*)&xs[0][0];
    xsv[t] = xg[t];
    xsv[t + 256] = xg[t + 256];
    __syncthreads();
    int c = t & 127;
    int rg = t >> 7;  // 0 or 1
    float acc[8] = {0, 0, 0, 0, 0, 0, 0, 0};
    #pragma unroll 4
    for (int k = 0; k < 128; ++k) {
        float wv = W[k * 128 + c];  // coalesced, L2-resident
        #pragma unroll
        for (int q = 0; q < 8; ++q) acc[q] += xs[rg * 8 + q][k] * wv;
    }
    int b = (int)(R0 >> 12);
    int i = (int)(R0 & 4095);
    half8 hv;
    #pragma unroll
    for (int q = 0; q < 8; ++q) hv[q] = (f16)acc[q];
    *(half8*)(hT + ((long)(b * 128 + c) * 4096 + i + rg * 8)) = hv;
}

// ---------------- k_e: e_src/e_dst = x @ Wa --------------------------------
__global__ __launch_bounds__(256) void k_e(const float* __restrict__ x,
                                           const float* __restrict__ Wa,
                                           float* __restrict__ e_src,
                                           float* __restrict__ e_dst) {
    int t = threadIdx.x;
    int lane = t & 63;
    int w = t >> 6;
    long rg = (long)blockIdx.x * 4 + w;
    const float* xr = x + rg * 128;
    float x0 = xr[lane], x1 = xr[lane + 64];
    float s = x0 * Wa[lane] + x1 * Wa[lane + 64];
    float d = x0 * Wa[128 + lane] + x1 * Wa[192 + lane];
    #pragma unroll
    for (int off = 32; off; off >>= 1) {
        s += __shfl_xor(s, off, 64);
        d += __shfl_xor(d, off, 64);
    }
    if (lane == 0) { e_src[rg] = s; e_dst[rg] = d; }
}

// ---------------- k_stats: per-row softmax max & 1/sum ---------------------
__global__ __launch_bounds__(256) void k_stats(const int* __restrict__ adj,
                                               const float* __restrict__ e_src,
                                               const float* __restrict__ e_dst,
                                               float* __restrict__ stat_m,
                                               float* __restrict__ stat_inv) {
    int bx = blockIdx.x;
    int b = bx & 3;       // b-copies of a row adjacent -> adj row fetched once
    int i = bx >> 2;
    long rg = (long)b * N_ + i;
    int t = threadIdx.x;
    float es = e_src[rg];
    const int* arow = adj + (long)i * N_;
    const float* ed = e_dst + (long)b * N_;
    float p[16];
    float m = NEG;
    #pragma unroll
    for (int c = 0; c < 16; ++c) {
        int j = t + 256 * c;
        int a = arow[j];
        float e = es + ed[j];
        e = (e >= 0.f) ? e : 0.2f * e;  // leaky relu
        e = a ? e : NEG;                // mask
        p[c] = e;
        m = fmaxf(m, e);
    }
    #pragma unroll
    for (int off = 32; off; off >>= 1) m = fmaxf(m, __shfl_xor(m, off, 64));
    __shared__ float sred[8];
    int lane = t & 63, wid = t >> 6;
    if (lane == 0) sred[wid] = m;
    __syncthreads();
    m = fmaxf(fmaxf(sred[0], sred[1]), fmaxf(sred[2], sred[3]));
    float sum = 0.f;
    #pragma unroll
    for (int c = 0; c < 16; ++c) sum += __expf(p[c] - m);
    #pragma unroll
    for (int off = 32; off; off >>= 1) sum += __shfl_xor(sum, off, 64);
    if (lane == 0) sred[4 + wid] = sum;
    __syncthreads();
    if (t == 0) {
        sum = sred[4] + sred[5] + sred[6] + sred[7];
        float inv = (m <= -1e29f) ? 0.f : 1.f / sum;  // all-masked -> 0
        stat_m[rg] = m;
        stat_inv[rg] = inv;
    }
}

// ---------------- k_fused: recompute p, write attn, MFMA out ---------------
// 16-row tiles, 4 waves = col quarters (x4 redundant p compute, wave 0 writes
// attn). No LDS, no barriers. attn is written once and NEVER re-read.
__device__ __forceinline__ void tile_step(
    const int* Aj, const float* Ed, const f16* Bp, float* Ao,
    int j0, int jn, float es, float m, float inv, int q4,
    int4& a0c, int4& a1c, float4& e0c, float4& e1c,
    int4& a0n, int4& a1n, float4& e0n, float4& e1n,
    f32x4& acc0, f32x4& acc1) {
    // prefetch next tile's adj/ed
    a0n = *(const int4*)(Aj + jn);
    a1n = *(const int4*)(Aj + jn + 4);
    e0n = *(const float4*)(Ed + jn);
    e1n = *(const float4*)(Ed + jn + 4);
    // B fragments for this tile (L2-resident hT)
    half8 bf0 = *(const half8*)(Bp + j0);
    half8 bf1 = *(const half8*)(Bp + j0 + 16 * N_);
    int am[8] = {a0c.x, a0c.y, a0c.z, a0c.w, a1c.x, a1c.y, a1c.z, a1c.w};
    float ev[8] = {e0c.x, e0c.y, e0c.z, e0c.w, e1c.x, e1c.y, e1c.z, e1c.w};
    float pv[8];
    #pragma unroll
    for (int q = 0; q < 8; ++q) {
        float e = es + ev[q];
        e = (e >= 0.f) ? e : 0.2f * e;   // leaky relu
        e = am[q] ? e : NEG;             // mask
        pv[q] = __expf(e - m);           // unnormalized (<=1); masked -> 0
    }
    if (q4 == 0) {
        f32x4 w0 = {pv[0] * inv, pv[1] * inv, pv[2] * inv, pv[3] * inv};
        f32x4 w1 = {pv[4] * inv, pv[5] * inv, pv[6] * inv, pv[7] * inv};
        __builtin_nontemporal_store(w0, (f32x4*)(Ao + j0));
        __builtin_nontemporal_store(w1, (f32x4*)(Ao + j0 + 4));
    }
    half8 af;
    #pragma unroll
    for (int q = 0; q < 8; ++q) af[q] = (f16)pv[q];
    acc0 = __builtin_amdgcn_mfma_f32_16x16x32_f16(af, bf0, acc0, 0, 0, 0);
    acc1 = __builtin_amdgcn_mfma_f32_16x16x32_f16(af, bf1, acc1, 0, 0, 0);
}

__global__ __launch_bounds__(256) void k_fused(const int* __restrict__ adj,
                                               const float* __restrict__ e_src,
                                               const float* __restrict__ e_dst,
                                               const float* __restrict__ stat_m,
                                               const float* __restrict__ stat_inv,
                                               const f16* __restrict__ hT,
                                               float* __restrict__ attn,
                                               float* __restrict__ out) {
    int t = threadIdx.x;
    int lane = t & 63, wid = t >> 6;
    int bx = blockIdx.x;
    int b = bx >> 8;               // 256 16-row tiles per batch
    int i0 = (bx & 255) * 16;
    int r16 = lane & 15;
    int kq = (lane >> 4) * 8;
    int q4 = wid;                  // column quarter 0..3
    int row = i0 + r16;
    long rg = (long)b * N_ + row;
    float es = e_src[rg];
    float m = stat_m[rg];
    float inv = stat_inv[rg];
    const int* Aj = adj + (long)row * N_ + kq;
    const float* Ed = e_dst + (long)b * N_ + kq;
    float* Ao = attn + rg * (long)N_ + kq;
    const f16* Bp = hT + ((long)(b * F_ + q4 * 32 + r16)) * N_ + kq;

    f32x4 acc0 = {0, 0, 0, 0}, acc1 = {0, 0, 0, 0};

    int4 a0A, a1A, a0B, a1B;
    float4 e0A, e1A, e0B, e1B;
    a0A = *(const int4*)(Aj);
    a1A = *(const int4*)(Aj + 4);
    e0A = *(const float4*)(Ed);
    e1A = *(const float4*)(Ed + 4);

    for (int jt = 0; jt < 128; jt += 2) {
        int j0 = jt * 32;
        int jn2 = (jt + 2 < 128) ? (j0 + 64) : 0;  // clamp to avoid OOB
        tile_step(Aj, Ed, Bp, Ao, j0, j0 + 32, es, m, inv, q4,
                  a0A, a1A, e0A, e1A, a0B, a1B, e0B, e1B, acc0, acc1);
        tile_step(Aj, Ed, Bp, Ao, j0 + 32, jn2, es, m, inv, q4,
                  a0B, a1B, e0B, e1B, a0A, a1A, e0A, e1A, acc0, acc1);
    }

    // epilogue: D row = (lane>>4)*4 + reg, col = q4*32 + nt*16 + r16
    float4 inv4 = *(const float4*)(stat_inv + (long)b * N_ + i0 + (lane >> 4) * 4);
    float invr[4] = {inv4.x, inv4.y, inv4.z, inv4.w};
    int rbase = i0 + (lane >> 4) * 4;
    float* ob = out + (long)b * N_ * F_;
    int col0 = q4 * 32 + r16;
    #pragma unroll
    for (int reg = 0; reg < 4; ++reg) {
        ob[(long)(rbase + reg) * F_ + col0]      = acc0[reg] * invr[reg];
        ob[(long)(rbase + reg) * F_ + col0 + 16] = acc1[reg] * invr[reg];
    }
}

extern "C" void kernel_launch(void* const* d_in, const int* in_sizes, int n_in,
                              void* d_out, int out_size, void* d_ws, size_t ws_size,
                              hipStream_t stream) {
    const float* x     = (const float*)d_in[0];
    const int*   adj   = (const int*)d_in[1];
    const float* W     = (const float*)d_in[2];
    const float* a_src = (const float*)d_in[3];
    const float* a_dst = (const float*)d_in[4];
    float* out  = (float*)d_out;
    float* attn = out + (long)B_ * N_ * F_;  // outputs concatenated: out, then attn

    char* ws = (char*)d_ws;
    float* Wa       = (float*)(ws + 0);        // 256 f32
    float* e_src    = (float*)(ws + 1024);     // 16384 f32
    float* e_dst    = (float*)(ws + 66560);    // 16384 f32
    f16*   hT       = (f16*)(ws + 132096);     // 4*128*4096 f16 = 4 MB
    float* stat_m   = (float*)(ws + 4326400);  // 16384 f32
    float* stat_inv = (float*)(ws + 4391936);  // 16384 f32

    k_wa<<<dim3(1), dim3(128), 0, stream>>>(W, a_src, a_dst, Wa);
    k_e<<<dim3((B_ * N_) / 4), dim3(256), 0, stream>>>(x, Wa, e_src, e_dst);
    k_h<<<dim3((B_ * N_) / 16), dim3(256), 0, stream>>>(x, W, hT);
    k_stats<<<dim3(B_ * N_), dim3(256), 0, stream>>>(adj, e_src, e_dst, stat_m, stat_inv);
    k_fused<<<dim3(B_ * (N_ / 16)), dim3(256), 0, stream>>>(adj, e_src, e_dst, stat_m,
                                                            stat_inv, hT, attn, out);
}